// Round 1
// baseline (113.573 us; speedup 1.0000x reference)
//
#include <hip/hip_runtime.h>
#include <math.h>

#define SS 8
#define CC 16
#define HH 64
#define WW 96
#define DD 64
#define NN (HH*WW)

// Prep: transpose src (S,C,H,W)->(S,H,W,C), cur (C,H,W)->(H,W,C),
// compute per-source folded projection matrices M = P[:,:3]*invK[:3,:3], t = P[:,3],
// and the 64 log-spaced depths.
__global__ __launch_bounds__(256) void prep_kernel(
    const float* __restrict__ cur, const float* __restrict__ src,
    const float* __restrict__ ext, const float* __restrict__ Ks,
    const float* __restrict__ invK, const float* __restrict__ mnp,
    const float* __restrict__ mxp,
    float* __restrict__ srcT, float* __restrict__ curT,
    float* __restrict__ mats, float* __restrict__ depths)
{
    int tid = blockIdx.x * 256 + threadIdx.x;
    const int srcElems = SS * CC * HH * WW;
    if (tid < srcElems) {
        int c = tid & 15;
        int r = tid >> 4;
        int w = r % WW;
        int r2 = r / WW;
        int h = r2 % HH;
        int s = r2 / HH;
        srcT[tid] = src[((s * CC + c) * HH + h) * WW + w];
    } else if (tid < srcElems + CC * HH * WW) {
        int t2 = tid - srcElems;
        int c = t2 & 15;
        int r = t2 >> 4;
        int w = r % WW;
        int h = r / WW;
        curT[t2] = cur[(c * HH + h) * WW + w];
    }
    if (blockIdx.x == 0) {
        if (threadIdx.x < DD) {
            float lmn = logf(mnp[0]);
            float lr  = logf(mxp[0] / mnp[0]);
            depths[threadIdx.x] = expf(lmn + lr * ((float)threadIdx.x * (1.0f / (DD - 1))));
        } else if (threadIdx.x < DD + SS) {
            int s = threadIdx.x - DD;
            float P[3][4];
            for (int i = 0; i < 3; ++i)
                for (int j = 0; j < 4; ++j) {
                    float a = 0.f;
                    for (int k = 0; k < 4; ++k)
                        a += Ks[s * 16 + i * 4 + k] * ext[s * 16 + k * 4 + j];
                    P[i][j] = a;
                }
            for (int i = 0; i < 3; ++i) {
                for (int j = 0; j < 3; ++j) {
                    float a = 0.f;
                    for (int k = 0; k < 3; ++k)
                        a += P[i][k] * invK[k * 4 + j];
                    mats[s * 12 + i * 3 + j] = a;
                }
                mats[s * 12 + 9 + i] = P[i][3];
            }
        }
    }
}

// Main: one thread per (d, n). Channel-last layouts make each bilinear tap
// a contiguous 64B (4x float4) read; dot with cur vector, weight, mask, sum over s.
__global__ __launch_bounds__(256) void cost_kernel(
    const float* __restrict__ curT, const float* __restrict__ srcT,
    const float* __restrict__ mats, const float* __restrict__ depths,
    float* __restrict__ out)
{
    __shared__ float sM[SS * 12];
    __shared__ float sD[DD];
    int tid = threadIdx.x;
    if (tid < SS * 12) sM[tid] = mats[tid];
    if (tid < DD) sD[tid] = depths[tid];
    __syncthreads();

    const int blocksPerD = NN / 256;             // 24
    int d = blockIdx.x / blocksPerD;
    int n = (blockIdx.x % blocksPerD) * 256 + tid;

    float x = (float)(n % WW) + 0.5f;
    float y = (float)(n / WW) + 0.5f;

    const float4* cp = (const float4*)(curT + n * CC);
    float4 c0 = cp[0], c1 = cp[1], c2 = cp[2], c3 = cp[3];
    float depth = sD[d];

    float acc = 0.f;
#pragma unroll
    for (int s = 0; s < SS; ++s) {
        const float* m = &sM[s * 12];
        float qx = m[0] * x + m[1] * y + m[2];
        float qy = m[3] * x + m[4] * y + m[5];
        float qz = m[6] * x + m[7] * y + m[8];
        float pz = depth * qz + m[11];
        if (pz > 0.f) {                           // mask = (z > 0); skip contributes 0
            float inv = 1.0f / (pz + 1e-8f);      // u = px/(z+EPS) per reference
            float u = (depth * qx + m[9])  * inv - 0.5f;
            float v = (depth * qy + m[10]) * inv - 0.5f;
            float x0f = floorf(u), y0f = floorf(v);
            float wx = u - x0f, wy = v - y0f;
            int x0 = (int)x0f, y0 = (int)y0f;
            float w00 = (1.f - wx) * (1.f - wy);
            float w10 = wx * (1.f - wy);
            float w01 = (1.f - wx) * wy;
            float w11 = wx * wy;
            const float* sbase = srcT + s * (HH * WW * CC);
#pragma unroll
            for (int t = 0; t < 4; ++t) {
                int xi = x0 + (t & 1);
                int yi = y0 + (t >> 1);
                float w = (t == 0) ? w00 : (t == 1) ? w10 : (t == 2) ? w01 : w11;
                bool valid = ((unsigned)xi < (unsigned)WW) && ((unsigned)yi < (unsigned)HH);
                int xc = min(max(xi, 0), WW - 1);
                int yc = min(max(yi, 0), HH - 1);
                const float4* p = (const float4*)(sbase + (yc * WW + xc) * CC);
                float4 a = p[0], b = p[1], e = p[2], f = p[3];
                float dt = a.x * c0.x + a.y * c0.y + a.z * c0.z + a.w * c0.w
                         + b.x * c1.x + b.y * c1.y + b.z * c1.z + b.w * c1.w
                         + e.x * c2.x + e.y * c2.y + e.z * c2.z + e.w * c2.w
                         + f.x * c3.x + f.y * c3.y + f.z * c3.z + f.w * c3.w;
                acc += (valid ? w : 0.f) * dt;
            }
        }
    }
    out[d * NN + n] = acc;                 // cost_volume
    out[DD * NN + d * NN + n] = depth;     // depth_planes
}

extern "C" void kernel_launch(void* const* d_in, const int* in_sizes, int n_in,
                              void* d_out, int out_size, void* d_ws, size_t ws_size,
                              hipStream_t stream) {
    const float* cur  = (const float*)d_in[0];
    const float* src  = (const float*)d_in[1];
    const float* ext  = (const float*)d_in[2];
    const float* Ks   = (const float*)d_in[3];
    const float* invK = (const float*)d_in[4];
    const float* mn   = (const float*)d_in[5];
    const float* mx   = (const float*)d_in[6];
    float* out = (float*)d_out;

    float* ws     = (float*)d_ws;
    float* srcT   = ws;                               // S*H*W*C = 786432
    float* curT   = srcT + SS * CC * HH * WW;         // H*W*C   =  98304
    float* mats   = curT + CC * HH * WW;              // 96
    float* depths = mats + SS * 12;                   // 64

    int prepBlocks = (SS * CC * HH * WW + CC * HH * WW) / 256;  // 3456
    prep_kernel<<<prepBlocks, 256, 0, stream>>>(cur, src, ext, Ks, invK, mn, mx,
                                                srcT, curT, mats, depths);
    cost_kernel<<<DD * (NN / 256), 256, 0, stream>>>(curT, srcT, mats, depths, out);
}

// Round 2
// 111.973 us; speedup vs baseline: 1.0143x; 1.0143x over previous
//
#include <hip/hip_runtime.h>
#include <math.h>

#define SS 8
#define CC 16
#define HH 64
#define WW 96
#define DD 64
#define NN (HH*WW)

// Prep: transpose src (S,C,H,W)->(S,H,W,C) and cur (C,H,W)->(H,W,C) with
// coalesced reads (lane = pixel, loop over c: each channel stream is contiguous)
// and contiguous 64B float4 writes per thread. Also folded projection matrices
// M = (Ks*ext)[:, :3]*invK[:3,:3], t = (Ks*ext)[:,3], and the 64 log depths.
__global__ __launch_bounds__(256) void prep_kernel(
    const float* __restrict__ cur, const float* __restrict__ src,
    const float* __restrict__ ext, const float* __restrict__ Ks,
    const float* __restrict__ invK, const float* __restrict__ mnp,
    const float* __restrict__ mxp,
    float* __restrict__ srcT, float* __restrict__ curT,
    float* __restrict__ mats, float* __restrict__ depths)
{
    int tid = blockIdx.x * 256 + threadIdx.x;
    const int srcPix = SS * NN;             // 49152
    if (tid < srcPix) {
        // s = tid / NN, p = tid % NN; read 16 channel streams (each coalesced
        // across lanes), write 16 contiguous floats.
        int p = tid % NN;
        int s = tid / NN;
        const float* base = src + (size_t)s * CC * NN + p;
        float v[CC];
#pragma unroll
        for (int c = 0; c < CC; ++c) v[c] = base[c * NN];
        float4* o = (float4*)(srcT + (size_t)tid * CC);
#pragma unroll
        for (int q = 0; q < 4; ++q)
            o[q] = make_float4(v[4*q], v[4*q+1], v[4*q+2], v[4*q+3]);
    } else if (tid < srcPix + NN) {
        int p = tid - srcPix;
        const float* base = cur + p;
        float v[CC];
#pragma unroll
        for (int c = 0; c < CC; ++c) v[c] = base[c * NN];
        float4* o = (float4*)(curT + (size_t)p * CC);
#pragma unroll
        for (int q = 0; q < 4; ++q)
            o[q] = make_float4(v[4*q], v[4*q+1], v[4*q+2], v[4*q+3]);
    }
    if (blockIdx.x == 0) {
        if (threadIdx.x < DD) {
            float lmn = logf(mnp[0]);
            float lr  = logf(mxp[0] / mnp[0]);
            depths[threadIdx.x] = expf(lmn + lr * ((float)threadIdx.x * (1.0f / (DD - 1))));
        } else if (threadIdx.x < DD + SS) {
            int s = threadIdx.x - DD;
            float P[3][4];
            for (int i = 0; i < 3; ++i)
                for (int j = 0; j < 4; ++j) {
                    float a = 0.f;
                    for (int k = 0; k < 4; ++k)
                        a += Ks[s * 16 + i * 4 + k] * ext[s * 16 + k * 4 + j];
                    P[i][j] = a;
                }
            for (int i = 0; i < 3; ++i) {
                for (int j = 0; j < 3; ++j) {
                    float a = 0.f;
                    for (int k = 0; k < 3; ++k)
                        a += P[i][k] * invK[k * 4 + j];
                    mats[s * 12 + i * 3 + j] = a;
                }
                mats[s * 12 + 9 + i] = P[i][3];
            }
        }
    }
}

// Main: one thread per (pixel n, depth pair {d, d+32}). Branchless over
// sources so loads for both depths x 4 taps pipeline; channel-last layout
// makes each tap 4x dwordx4.
__global__ __launch_bounds__(256) void cost_kernel(
    const float* __restrict__ curT, const float* __restrict__ srcT,
    const float* __restrict__ mats, const float* __restrict__ depths,
    float* __restrict__ out)
{
    __shared__ float sM[SS * 12];
    __shared__ float sD[DD];
    int tid = threadIdx.x;
    if (tid < SS * 12) sM[tid] = mats[tid];
    if (tid < DD) sD[tid] = depths[tid];
    __syncthreads();

    const int blocksPerD = NN / 256;              // 24
    int dlo = blockIdx.x / blocksPerD;            // 0..31
    int n = (blockIdx.x % blocksPerD) * 256 + tid;

    float x = (float)(n % WW) + 0.5f;
    float y = (float)(n / WW) + 0.5f;

    const float4* cp = (const float4*)(curT + (size_t)n * CC);
    float4 c0 = cp[0], c1 = cp[1], c2 = cp[2], c3 = cp[3];

    float dep[2] = { sD[dlo], sD[dlo + 32] };
    float acc[2] = { 0.f, 0.f };

#pragma unroll
    for (int s = 0; s < SS; ++s) {
        const float* m = &sM[s * 12];
        float qx = m[0] * x + m[1] * y + m[2];
        float qy = m[3] * x + m[4] * y + m[5];
        float qz = m[6] * x + m[7] * y + m[8];
#pragma unroll
        for (int k = 0; k < 2; ++k) {
            float depth = dep[k];
            float pz = depth * qz + m[11];
            bool ok = pz > 0.f;
            float inv = 1.0f / (pz + 1e-8f);
            // branchless: invalid depth -> coords far out of bounds -> all
            // taps invalid -> contribution 0 (matches mask semantics, no NaN)
            float u = ok ? (depth * qx + m[9])  * inv - 0.5f : -8.0f;
            float v = ok ? (depth * qy + m[10]) * inv - 0.5f : -8.0f;
            float x0f = floorf(u), y0f = floorf(v);
            float wx = u - x0f, wy = v - y0f;
            int x0 = (int)x0f, y0 = (int)y0f;
            float w00 = (1.f - wx) * (1.f - wy);
            float w10 = wx * (1.f - wy);
            float w01 = (1.f - wx) * wy;
            float w11 = wx * wy;
            const float* sbase = srcT + (size_t)s * (NN * CC);
#pragma unroll
            for (int t = 0; t < 4; ++t) {
                int xi = x0 + (t & 1);
                int yi = y0 + (t >> 1);
                float w = (t == 0) ? w00 : (t == 1) ? w10 : (t == 2) ? w01 : w11;
                bool valid = ((unsigned)xi < (unsigned)WW) && ((unsigned)yi < (unsigned)HH);
                int xc = min(max(xi, 0), WW - 1);
                int yc = min(max(yi, 0), HH - 1);
                const float4* p = (const float4*)(sbase + (size_t)(yc * WW + xc) * CC);
                float4 a = p[0], b = p[1], e = p[2], f = p[3];
                float dt = a.x * c0.x + a.y * c0.y + a.z * c0.z + a.w * c0.w
                         + b.x * c1.x + b.y * c1.y + b.z * c1.z + b.w * c1.w
                         + e.x * c2.x + e.y * c2.y + e.z * c2.z + e.w * c2.w
                         + f.x * c3.x + f.y * c3.y + f.z * c3.z + f.w * c3.w;
                acc[k] += (valid ? w : 0.f) * dt;
            }
        }
    }
    out[(size_t)dlo * NN + n] = acc[0];
    out[(size_t)(dlo + 32) * NN + n] = acc[1];
    out[(size_t)DD * NN + (size_t)dlo * NN + n] = dep[0];
    out[(size_t)DD * NN + (size_t)(dlo + 32) * NN + n] = dep[1];
}

extern "C" void kernel_launch(void* const* d_in, const int* in_sizes, int n_in,
                              void* d_out, int out_size, void* d_ws, size_t ws_size,
                              hipStream_t stream) {
    const float* cur  = (const float*)d_in[0];
    const float* src  = (const float*)d_in[1];
    const float* ext  = (const float*)d_in[2];
    const float* Ks   = (const float*)d_in[3];
    const float* invK = (const float*)d_in[4];
    const float* mn   = (const float*)d_in[5];
    const float* mx   = (const float*)d_in[6];
    float* out = (float*)d_out;

    float* ws     = (float*)d_ws;
    float* srcT   = ws;                               // S*H*W*C = 786432
    float* curT   = srcT + SS * CC * HH * WW;         // H*W*C   =  98304
    float* mats   = curT + CC * HH * WW;              // 96
    float* depths = mats + SS * 12;                   // 64

    int prepThreads = SS * NN + NN;                   // 55296
    int prepBlocks = (prepThreads + 255) / 256;       // 216
    prep_kernel<<<prepBlocks, 256, 0, stream>>>(cur, src, ext, Ks, invK, mn, mx,
                                                srcT, curT, mats, depths);
    cost_kernel<<<(DD / 2) * (NN / 256), 256, 0, stream>>>(curT, srcT, mats, depths, out);
}

// Round 3
// 90.381 us; speedup vs baseline: 1.2566x; 1.2389x over previous
//
#include <hip/hip_runtime.h>
#include <math.h>

#define SS 8
#define CC 16
#define HH 64
#define WW 96
#define DD 64
#define NN (HH*WW)

typedef _Float16 h2 __attribute__((ext_vector_type(2)));
struct alignas(16) H8 { h2 v[4]; };   // 8 halfs = 16 B

// Prep: transpose+convert src (S,C,H,W)->f16 (S,H,W,C), cur (C,H,W)->f16 (H,W,C).
// Reads are coalesced (lane = pixel, per-channel contiguous streams); writes are
// 2x dwordx4 per thread. Also folded projection matrices and 64 log depths.
__global__ __launch_bounds__(256) void prep_kernel(
    const float* __restrict__ cur, const float* __restrict__ src,
    const float* __restrict__ ext, const float* __restrict__ Ks,
    const float* __restrict__ invK, const float* __restrict__ mnp,
    const float* __restrict__ mxp,
    _Float16* __restrict__ srcT, _Float16* __restrict__ curT,
    float* __restrict__ mats, float* __restrict__ depths)
{
    int tid = blockIdx.x * 256 + threadIdx.x;
    const int srcPix = SS * NN;             // 49152
    if (tid < srcPix) {
        int p = tid % NN;
        int s = tid / NN;
        const float* base = src + (size_t)s * CC * NN + p;
        _Float16 v[CC];
#pragma unroll
        for (int c = 0; c < CC; ++c) v[c] = (_Float16)base[c * NN];
        ((H8*)(srcT + (size_t)tid * CC))[0] = *(H8*)&v[0];
        ((H8*)(srcT + (size_t)tid * CC))[1] = *(H8*)&v[8];
    } else if (tid < srcPix + NN) {
        int p = tid - srcPix;
        const float* base = cur + p;
        _Float16 v[CC];
#pragma unroll
        for (int c = 0; c < CC; ++c) v[c] = (_Float16)base[c * NN];
        ((H8*)(curT + (size_t)p * CC))[0] = *(H8*)&v[0];
        ((H8*)(curT + (size_t)p * CC))[1] = *(H8*)&v[8];
    }
    if (blockIdx.x == 0) {
        if (threadIdx.x < DD) {
            float lmn = logf(mnp[0]);
            float lr  = logf(mxp[0] / mnp[0]);
            depths[threadIdx.x] = expf(lmn + lr * ((float)threadIdx.x * (1.0f / (DD - 1))));
        } else if (threadIdx.x < DD + SS) {
            int s = threadIdx.x - DD;
            float P[3][4];
            for (int i = 0; i < 3; ++i)
                for (int j = 0; j < 4; ++j) {
                    float a = 0.f;
                    for (int k = 0; k < 4; ++k)
                        a += Ks[s * 16 + i * 4 + k] * ext[s * 16 + k * 4 + j];
                    P[i][j] = a;
                }
            for (int i = 0; i < 3; ++i) {
                for (int j = 0; j < 3; ++j) {
                    float a = 0.f;
                    for (int k = 0; k < 3; ++k)
                        a += P[i][k] * invK[k * 4 + j];
                    mats[s * 12 + i * 3 + j] = a;
                }
                mats[s * 12 + 9 + i] = P[i][3];
            }
        }
    }
}

// Main: one thread per (d, n), branchless over sources. f16 channel-last taps:
// 2x dwordx4 per tap, 8x v_dot2_f32_f16 per tap.
__global__ __launch_bounds__(256) void cost_kernel(
    const _Float16* __restrict__ curT, const _Float16* __restrict__ srcT,
    const float* __restrict__ mats, const float* __restrict__ depths,
    float* __restrict__ out)
{
    __shared__ float sM[SS * 12];
    __shared__ float sD[DD];
    int tid = threadIdx.x;
    if (tid < SS * 12) sM[tid] = mats[tid];
    if (tid < DD) sD[tid] = depths[tid];
    __syncthreads();

    const int blocksPerD = NN / 256;              // 24
    int d = blockIdx.x / blocksPerD;              // 0..63
    int n = (blockIdx.x % blocksPerD) * 256 + tid;

    float x = (float)(n % WW) + 0.5f;
    float y = (float)(n / WW) + 0.5f;

    const H8* cp = (const H8*)(curT + (size_t)n * CC);
    H8 cA = cp[0], cB = cp[1];
    float depth = sD[d];

    float acc = 0.f;
#pragma unroll
    for (int s = 0; s < SS; ++s) {
        const float* m = &sM[s * 12];
        float qx = m[0] * x + m[1] * y + m[2];
        float qy = m[3] * x + m[4] * y + m[5];
        float qz = m[6] * x + m[7] * y + m[8];
        float pz = depth * qz + m[11];
        bool ok = pz > 0.f;
        float inv = 1.0f / (pz + 1e-8f);
        // invalid depth -> coords far out of bounds -> all taps invalid -> 0
        float u = ok ? (depth * qx + m[9])  * inv - 0.5f : -8.0f;
        float v = ok ? (depth * qy + m[10]) * inv - 0.5f : -8.0f;
        float x0f = floorf(u), y0f = floorf(v);
        float wx = u - x0f, wy = v - y0f;
        int x0 = (int)x0f, y0 = (int)y0f;
        float w00 = (1.f - wx) * (1.f - wy);
        float w10 = wx * (1.f - wy);
        float w01 = (1.f - wx) * wy;
        float w11 = wx * wy;
        const _Float16* sbase = srcT + (size_t)s * (NN * CC);
#pragma unroll
        for (int t = 0; t < 4; ++t) {
            int xi = x0 + (t & 1);
            int yi = y0 + (t >> 1);
            float w = (t == 0) ? w00 : (t == 1) ? w10 : (t == 2) ? w01 : w11;
            bool valid = ((unsigned)xi < (unsigned)WW) && ((unsigned)yi < (unsigned)HH);
            int xc = min(max(xi, 0), WW - 1);
            int yc = min(max(yi, 0), HH - 1);
            const H8* p = (const H8*)(sbase + (size_t)(yc * WW + xc) * CC);
            H8 a = p[0], b = p[1];
            float dt = 0.f;
#pragma unroll
            for (int q = 0; q < 4; ++q)
                dt = __builtin_amdgcn_fdot2(a.v[q], cA.v[q], dt, false);
#pragma unroll
            for (int q = 0; q < 4; ++q)
                dt = __builtin_amdgcn_fdot2(b.v[q], cB.v[q], dt, false);
            acc += (valid ? w : 0.f) * dt;
        }
    }
    out[(size_t)d * NN + n] = acc;                 // cost_volume
    out[(size_t)DD * NN + (size_t)d * NN + n] = depth;  // depth_planes
}

extern "C" void kernel_launch(void* const* d_in, const int* in_sizes, int n_in,
                              void* d_out, int out_size, void* d_ws, size_t ws_size,
                              hipStream_t stream) {
    const float* cur  = (const float*)d_in[0];
    const float* src  = (const float*)d_in[1];
    const float* ext  = (const float*)d_in[2];
    const float* Ks   = (const float*)d_in[3];
    const float* invK = (const float*)d_in[4];
    const float* mn   = (const float*)d_in[5];
    const float* mx   = (const float*)d_in[6];
    float* out = (float*)d_out;

    char* ws = (char*)d_ws;
    _Float16* srcT = (_Float16*)ws;                         // S*N*C halfs = 1.5 MB
    _Float16* curT = srcT + (size_t)SS * NN * CC;           // N*C halfs
    float* mats    = (float*)(curT + (size_t)NN * CC);      // 96
    float* depths  = mats + SS * 12;                        // 64

    int prepThreads = SS * NN + NN;                         // 55296
    int prepBlocks = (prepThreads + 255) / 256;             // 216
    prep_kernel<<<prepBlocks, 256, 0, stream>>>(cur, src, ext, Ks, invK, mn, mx,
                                                srcT, curT, mats, depths);
    cost_kernel<<<DD * (NN / 256), 256, 0, stream>>>(curT, srcT, mats, depths, out);
}

// Round 4
// 89.895 us; speedup vs baseline: 1.2634x; 1.0054x over previous
//
#include <hip/hip_runtime.h>
#include <math.h>

#define SS 8
#define CC 16
#define HH 64
#define WW 96
#define DD 64
#define NN (HH*WW)
#define PW 100            // padded width: 2 zero cols each side
#define PH 66             // padded height: 1 zero row each side
#define PN (PH*PW)        // 6600 padded pixels per source

typedef _Float16 h2 __attribute__((ext_vector_type(2)));
struct alignas(16) H8 { h2 v[4]; };   // 8 halfs = 16 B

// Prep: transpose+convert src (S,C,H,W) -> f16 zero-padded channel-last
// (S, PH, PW, C); cur (C,H,W) -> f16 (H,W,C). Border texels written as zeros
// so OOB bilinear taps read 0 with no per-tap masking in the main kernel.
// Also folded projection matrices and the 64 log-spaced depths.
__global__ __launch_bounds__(256) void prep_kernel(
    const float* __restrict__ cur, const float* __restrict__ src,
    const float* __restrict__ ext, const float* __restrict__ Ks,
    const float* __restrict__ invK, const float* __restrict__ mnp,
    const float* __restrict__ mxp,
    _Float16* __restrict__ srcT, _Float16* __restrict__ curT,
    float* __restrict__ mats, float* __restrict__ depths)
{
    int tid = blockIdx.x * 256 + threadIdx.x;
    const int srcPad = SS * PN;             // 52800
    if (tid < srcPad) {
        int s = tid / PN;
        int rem = tid % PN;
        int py = rem / PW;
        int px = rem % PW;
        _Float16 v[CC] = {};                // zeros for border texels
        if (py >= 1 && py <= HH && px >= 2 && px <= WW + 1) {
            int p = (py - 1) * WW + (px - 2);
            const float* base = src + (size_t)s * CC * NN + p;
#pragma unroll
            for (int c = 0; c < CC; ++c) v[c] = (_Float16)base[c * NN];
        }
        H8* o = (H8*)(srcT + (size_t)tid * CC);
        o[0] = *(H8*)&v[0];
        o[1] = *(H8*)&v[8];
    } else if (tid < srcPad + NN) {
        int p = tid - srcPad;
        const float* base = cur + p;
        _Float16 v[CC];
#pragma unroll
        for (int c = 0; c < CC; ++c) v[c] = (_Float16)base[c * NN];
        H8* o = (H8*)(curT + (size_t)p * CC);
        o[0] = *(H8*)&v[0];
        o[1] = *(H8*)&v[8];
    }
    if (blockIdx.x == 0) {
        if (threadIdx.x < DD) {
            float lmn = logf(mnp[0]);
            float lr  = logf(mxp[0] / mnp[0]);
            depths[threadIdx.x] = expf(lmn + lr * ((float)threadIdx.x * (1.0f / (DD - 1))));
        } else if (threadIdx.x < DD + SS) {
            int s = threadIdx.x - DD;
            float P[3][4];
            for (int i = 0; i < 3; ++i)
                for (int j = 0; j < 4; ++j) {
                    float a = 0.f;
                    for (int k = 0; k < 4; ++k)
                        a += Ks[s * 16 + i * 4 + k] * ext[s * 16 + k * 4 + j];
                    P[i][j] = a;
                }
            for (int i = 0; i < 3; ++i) {
                for (int j = 0; j < 3; ++j) {
                    float a = 0.f;
                    for (int k = 0; k < 3; ++k)
                        a += P[i][k] * invK[k * 4 + j];
                    mats[s * 12 + i * 3 + j] = a;
                }
                mats[s * 12 + 9 + i] = P[i][3];
            }
        }
    }
}

// Main: one thread per (d, n). Padded layout: two contiguous 64B row-pair
// loads per source (no validity masks), factored bilinear lerp, fast rcp.
__global__ __launch_bounds__(256) void cost_kernel(
    const _Float16* __restrict__ curT, const _Float16* __restrict__ srcT,
    const float* __restrict__ mats, const float* __restrict__ depths,
    float* __restrict__ out)
{
    __shared__ float sM[SS * 12];
    __shared__ float sD[DD];
    int tid = threadIdx.x;
    if (tid < SS * 12) sM[tid] = mats[tid];
    if (tid < DD) sD[tid] = depths[tid];
    __syncthreads();

    const int blocksPerD = NN / 256;              // 24
    int d = blockIdx.x / blocksPerD;              // 0..63
    int n = (blockIdx.x % blocksPerD) * 256 + tid;

    float x = (float)(n % WW) + 0.5f;
    float y = (float)(n / WW) + 0.5f;

    const H8* cp = (const H8*)(curT + (size_t)n * CC);
    H8 cA = cp[0], cB = cp[1];
    float depth = sD[d];

    float acc = 0.f;
#pragma unroll
    for (int s = 0; s < SS; ++s) {
        const float* m = &sM[s * 12];
        float qx = m[0] * x + m[1] * y + m[2];
        float qy = m[3] * x + m[4] * y + m[5];
        float qz = m[6] * x + m[7] * y + m[8];
        float pz = depth * qz + m[11];
        bool ok = pz > 0.f;
        float r = __builtin_amdgcn_rcpf(pz + 1e-8f);   // u = px/(z+EPS) per ref
        // invalid depth -> far OOB -> taps land in zero border -> contributes 0
        float u = ok ? (depth * qx + m[9])  * r - 0.5f : -8.0f;
        float v = ok ? (depth * qy + m[10]) * r - 0.5f : -8.0f;
        float x0f = floorf(u), y0f = floorf(v);
        float wx = u - x0f, wy = v - y0f;
        // padded indices: +2 col offset, +1 row offset; clamps keep both taps
        // of each pair inside the padded image and in the zero border when OOB
        int x0p = min(max((int)x0f + 2, 0), WW + 2);   // [0, 98]
        int y0p = min(max((int)y0f + 1, 0), PH - 1);   // [0, 65]
        int y1p = min(max((int)y0f + 2, 0), PH - 1);
        const _Float16* sbase = srcT + (size_t)s * (PN * CC);
        const H8* r0 = (const H8*)(sbase + (size_t)(y0p * PW + x0p) * CC);
        const H8* r1 = (const H8*)(sbase + (size_t)(y1p * PW + x0p) * CC);
        H8 a0 = r0[0], a1 = r0[1], a2 = r0[2], a3 = r0[3];   // row0: left|right tap
        H8 b0 = r1[0], b1 = r1[1], b2 = r1[2], b3 = r1[3];   // row1: left|right tap
        float dL0 = 0.f, dR0 = 0.f, dL1 = 0.f, dR1 = 0.f;
#pragma unroll
        for (int q = 0; q < 4; ++q) {
            dL0 = __builtin_amdgcn_fdot2(a0.v[q], cA.v[q], dL0, false);
            dL0 = __builtin_amdgcn_fdot2(a1.v[q], cB.v[q], dL0, false);
            dR0 = __builtin_amdgcn_fdot2(a2.v[q], cA.v[q], dR0, false);
            dR0 = __builtin_amdgcn_fdot2(a3.v[q], cB.v[q], dR0, false);
            dL1 = __builtin_amdgcn_fdot2(b0.v[q], cA.v[q], dL1, false);
            dL1 = __builtin_amdgcn_fdot2(b1.v[q], cB.v[q], dL1, false);
            dR1 = __builtin_amdgcn_fdot2(b2.v[q], cA.v[q], dR1, false);
            dR1 = __builtin_amdgcn_fdot2(b3.v[q], cB.v[q], dR1, false);
        }
        float d0 = dL0 + wx * (dR0 - dL0);
        float d1 = dL1 + wx * (dR1 - dL1);
        acc += d0 + wy * (d1 - d0);
    }
    out[(size_t)d * NN + n] = acc;                      // cost_volume
    out[(size_t)DD * NN + (size_t)d * NN + n] = depth;  // depth_planes
}

extern "C" void kernel_launch(void* const* d_in, const int* in_sizes, int n_in,
                              void* d_out, int out_size, void* d_ws, size_t ws_size,
                              hipStream_t stream) {
    const float* cur  = (const float*)d_in[0];
    const float* src  = (const float*)d_in[1];
    const float* ext  = (const float*)d_in[2];
    const float* Ks   = (const float*)d_in[3];
    const float* invK = (const float*)d_in[4];
    const float* mn   = (const float*)d_in[5];
    const float* mx   = (const float*)d_in[6];
    float* out = (float*)d_out;

    char* ws = (char*)d_ws;
    _Float16* srcT = (_Float16*)ws;                     // S*PN*C halfs ≈ 1.69 MB
    _Float16* curT = srcT + (size_t)SS * PN * CC;       // N*C halfs
    float* mats    = (float*)(curT + (size_t)NN * CC);  // 96
    float* depths  = mats + SS * 12;                    // 64

    int prepThreads = SS * PN + NN;                     // 58944
    int prepBlocks = (prepThreads + 255) / 256;         // 231
    prep_kernel<<<prepBlocks, 256, 0, stream>>>(cur, src, ext, Ks, invK, mn, mx,
                                                srcT, curT, mats, depths);
    cost_kernel<<<DD * (NN / 256), 256, 0, stream>>>(curT, srcT, mats, depths, out);
}

// Round 5
// 84.260 us; speedup vs baseline: 1.3479x; 1.0669x over previous
//
#include <hip/hip_runtime.h>
#include <math.h>

#define SS 8
#define CC 16
#define HH 64
#define WW 96
#define DD 64
#define NN (HH*WW)
#define PW 100            // padded width: 2 zero cols each side
#define PH 66             // padded height: 1 zero row each side
#define PN (PH*PW)        // 6600 padded pixels per source

typedef _Float16 h2 __attribute__((ext_vector_type(2)));
struct alignas(16) H8 { h2 v[4]; };   // 8 halfs = 16 B

// Prep: transpose+convert src (S,C,H,W) -> f16 zero-padded channel-last
// (S, PH, PW, C); cur (C,H,W) -> f16 (H,W,C). Border texels written as zeros
// so OOB bilinear taps read 0 with no per-tap masking in the main kernel.
// Also folded projection matrices and the 64 log-spaced depths.
__global__ __launch_bounds__(256) void prep_kernel(
    const float* __restrict__ cur, const float* __restrict__ src,
    const float* __restrict__ ext, const float* __restrict__ Ks,
    const float* __restrict__ invK, const float* __restrict__ mnp,
    const float* __restrict__ mxp,
    _Float16* __restrict__ srcT, _Float16* __restrict__ curT,
    float* __restrict__ mats, float* __restrict__ depths)
{
    int tid = blockIdx.x * 256 + threadIdx.x;
    const int srcPad = SS * PN;             // 52800
    if (tid < srcPad) {
        int s = tid / PN;
        int rem = tid % PN;
        int py = rem / PW;
        int px = rem % PW;
        _Float16 v[CC] = {};                // zeros for border texels
        if (py >= 1 && py <= HH && px >= 2 && px <= WW + 1) {
            int p = (py - 1) * WW + (px - 2);
            const float* base = src + (size_t)s * CC * NN + p;
#pragma unroll
            for (int c = 0; c < CC; ++c) v[c] = (_Float16)base[c * NN];
        }
        H8* o = (H8*)(srcT + (size_t)tid * CC);
        o[0] = *(H8*)&v[0];
        o[1] = *(H8*)&v[8];
    } else if (tid < srcPad + NN) {
        int p = tid - srcPad;
        const float* base = cur + p;
        _Float16 v[CC];
#pragma unroll
        for (int c = 0; c < CC; ++c) v[c] = (_Float16)base[c * NN];
        H8* o = (H8*)(curT + (size_t)p * CC);
        o[0] = *(H8*)&v[0];
        o[1] = *(H8*)&v[8];
    }
    if (blockIdx.x == 0) {
        if (threadIdx.x < DD) {
            float lmn = logf(mnp[0]);
            float lr  = logf(mxp[0] / mnp[0]);
            depths[threadIdx.x] = expf(lmn + lr * ((float)threadIdx.x * (1.0f / (DD - 1))));
        } else if (threadIdx.x < DD + SS) {
            int s = threadIdx.x - DD;
            float P[3][4];
            for (int i = 0; i < 3; ++i)
                for (int j = 0; j < 4; ++j) {
                    float a = 0.f;
                    for (int k = 0; k < 4; ++k)
                        a += Ks[s * 16 + i * 4 + k] * ext[s * 16 + k * 4 + j];
                    P[i][j] = a;
                }
            for (int i = 0; i < 3; ++i) {
                for (int j = 0; j < 3; ++j) {
                    float a = 0.f;
                    for (int k = 0; k < 3; ++k)
                        a += P[i][k] * invK[k * 4 + j];
                    mats[s * 12 + i * 3 + j] = a;
                }
                mats[s * 12 + 9 + i] = P[i][3];
            }
        }
    }
}

// Main: block = 8x8 pixel tile x 4 consecutive depths (one depth per wave).
// Consecutive depths sample nearly the same texels -> ~4x smaller L1
// footprint and ~4x texel reuse vs one-depth-per-block mapping.
__global__ __launch_bounds__(256, 6) void cost_kernel(
    const _Float16* __restrict__ curT, const _Float16* __restrict__ srcT,
    const float* __restrict__ mats, const float* __restrict__ depths,
    float* __restrict__ out)
{
    __shared__ float sM[SS * 12];
    __shared__ float sD[DD];
    int tid = threadIdx.x;
    if (tid < SS * 12) sM[tid] = mats[tid];
    if (tid < DD) sD[tid] = depths[tid];
    __syncthreads();

    const int TX = WW / 8;                 // 12
    const int TY = HH / 8;                 // 8
    int bx = blockIdx.x;
    int dg  = bx / (TX * TY);              // 0..15
    int rem = bx % (TX * TY);
    int tyi = rem / TX;
    int txi = rem % TX;
    int lane = tid & 63;
    int dsub = tid >> 6;                   // wave index = depth sub-index
    int d  = dg * 4 + dsub;
    int px = txi * 8 + (lane & 7);
    int py = tyi * 8 + (lane >> 3);
    int n  = py * WW + px;

    float x = (float)px + 0.5f;
    float y = (float)py + 0.5f;

    const H8* cp = (const H8*)(curT + (size_t)n * CC);
    H8 cA = cp[0], cB = cp[1];
    float depth = sD[d];

    float acc = 0.f;
#pragma unroll 2
    for (int s = 0; s < SS; ++s) {
        const float* m = &sM[s * 12];
        float qx = m[0] * x + m[1] * y + m[2];
        float qy = m[3] * x + m[4] * y + m[5];
        float qz = m[6] * x + m[7] * y + m[8];
        float pz = depth * qz + m[11];
        bool ok = pz > 0.f;
        float r = __builtin_amdgcn_rcpf(pz + 1e-8f);   // u = px/(z+EPS) per ref
        // invalid depth -> far OOB -> taps land in zero border -> contributes 0
        float u = ok ? (depth * qx + m[9])  * r - 0.5f : -8.0f;
        float v = ok ? (depth * qy + m[10]) * r - 0.5f : -8.0f;
        float x0f = floorf(u), y0f = floorf(v);
        float wx = u - x0f, wy = v - y0f;
        // padded indices: +2 col offset, +1 row offset; clamps keep both taps
        // of each pair inside the padded image and in the zero border when OOB
        int x0p = min(max((int)x0f + 2, 0), WW + 2);   // [0, 98]
        int y0p = min(max((int)y0f + 1, 0), PH - 1);   // [0, 65]
        int y1p = min(max((int)y0f + 2, 0), PH - 1);
        const _Float16* sbase = srcT + (size_t)s * (PN * CC);
        const H8* r0 = (const H8*)(sbase + (size_t)(y0p * PW + x0p) * CC);
        const H8* r1 = (const H8*)(sbase + (size_t)(y1p * PW + x0p) * CC);
        H8 a0 = r0[0], a1 = r0[1], a2 = r0[2], a3 = r0[3];   // row0: left|right tap
        H8 b0 = r1[0], b1 = r1[1], b2 = r1[2], b3 = r1[3];   // row1: left|right tap
        float dL0 = 0.f, dR0 = 0.f, dL1 = 0.f, dR1 = 0.f;
#pragma unroll
        for (int q = 0; q < 4; ++q) {
            dL0 = __builtin_amdgcn_fdot2(a0.v[q], cA.v[q], dL0, false);
            dL0 = __builtin_amdgcn_fdot2(a1.v[q], cB.v[q], dL0, false);
            dR0 = __builtin_amdgcn_fdot2(a2.v[q], cA.v[q], dR0, false);
            dR0 = __builtin_amdgcn_fdot2(a3.v[q], cB.v[q], dR0, false);
            dL1 = __builtin_amdgcn_fdot2(b0.v[q], cA.v[q], dL1, false);
            dL1 = __builtin_amdgcn_fdot2(b1.v[q], cB.v[q], dL1, false);
            dR1 = __builtin_amdgcn_fdot2(b2.v[q], cA.v[q], dR1, false);
            dR1 = __builtin_amdgcn_fdot2(b3.v[q], cB.v[q], dR1, false);
        }
        float d0 = dL0 + wx * (dR0 - dL0);
        float d1 = dL1 + wx * (dR1 - dL1);
        acc += d0 + wy * (d1 - d0);
    }
    out[(size_t)d * NN + n] = acc;                      // cost_volume
    out[(size_t)DD * NN + (size_t)d * NN + n] = depth;  // depth_planes
}

extern "C" void kernel_launch(void* const* d_in, const int* in_sizes, int n_in,
                              void* d_out, int out_size, void* d_ws, size_t ws_size,
                              hipStream_t stream) {
    const float* cur  = (const float*)d_in[0];
    const float* src  = (const float*)d_in[1];
    const float* ext  = (const float*)d_in[2];
    const float* Ks   = (const float*)d_in[3];
    const float* invK = (const float*)d_in[4];
    const float* mn   = (const float*)d_in[5];
    const float* mx   = (const float*)d_in[6];
    float* out = (float*)d_out;

    char* ws = (char*)d_ws;
    _Float16* srcT = (_Float16*)ws;                     // S*PN*C halfs ≈ 1.69 MB
    _Float16* curT = srcT + (size_t)SS * PN * CC;       // N*C halfs
    float* mats    = (float*)(curT + (size_t)NN * CC);  // 96
    float* depths  = mats + SS * 12;                    // 64

    int prepThreads = SS * PN + NN;                     // 58944
    int prepBlocks = (prepThreads + 255) / 256;         // 231
    prep_kernel<<<prepBlocks, 256, 0, stream>>>(cur, src, ext, Ks, invK, mn, mx,
                                                srcT, curT, mats, depths);
    cost_kernel<<<(DD / 4) * (WW / 8) * (HH / 8), 256, 0, stream>>>(curT, srcT, mats, depths, out);
}

// Round 6
// 82.602 us; speedup vs baseline: 1.3749x; 1.0201x over previous
//
#include <hip/hip_runtime.h>
#include <math.h>

#define SS 8
#define CC 16
#define HH 64
#define WW 96
#define DD 64
#define NN (HH*WW)
#define PW 100            // padded width: 2 zero cols each side
#define PH 66             // padded height: 1 zero row each side
#define PN (PH*PW)        // 6600 padded pixels per source

typedef _Float16 h2 __attribute__((ext_vector_type(2)));
struct alignas(16) H8 { h2 v[4]; };   // 8 halfs = 16 B

// Prep: transpose+convert src (S,C,H,W) -> f16 zero-padded channel-last
// (S, PH, PW, C); cur (C,H,W) -> f16 (H,W,C). Border texels written as zeros
// so OOB bilinear taps read 0 with no per-tap masking in the main kernel.
// Also folded projection matrices and the 64 log-spaced depths.
__global__ __launch_bounds__(256) void prep_kernel(
    const float* __restrict__ cur, const float* __restrict__ src,
    const float* __restrict__ ext, const float* __restrict__ Ks,
    const float* __restrict__ invK, const float* __restrict__ mnp,
    const float* __restrict__ mxp,
    _Float16* __restrict__ srcT, _Float16* __restrict__ curT,
    float* __restrict__ mats, float* __restrict__ depths)
{
    int tid = blockIdx.x * 256 + threadIdx.x;
    const int srcPad = SS * PN;             // 52800
    if (tid < srcPad) {
        int s = tid / PN;
        int rem = tid % PN;
        int py = rem / PW;
        int px = rem % PW;
        _Float16 v[CC] = {};                // zeros for border texels
        if (py >= 1 && py <= HH && px >= 2 && px <= WW + 1) {
            int p = (py - 1) * WW + (px - 2);
            const float* base = src + (size_t)s * CC * NN + p;
#pragma unroll
            for (int c = 0; c < CC; ++c) v[c] = (_Float16)base[c * NN];
        }
        H8* o = (H8*)(srcT + (size_t)tid * CC);
        o[0] = *(H8*)&v[0];
        o[1] = *(H8*)&v[8];
    } else if (tid < srcPad + NN) {
        int p = tid - srcPad;
        const float* base = cur + p;
        _Float16 v[CC];
#pragma unroll
        for (int c = 0; c < CC; ++c) v[c] = (_Float16)base[c * NN];
        H8* o = (H8*)(curT + (size_t)p * CC);
        o[0] = *(H8*)&v[0];
        o[1] = *(H8*)&v[8];
    }
    if (blockIdx.x == 0) {
        if (threadIdx.x < DD) {
            float lmn = logf(mnp[0]);
            float lr  = logf(mxp[0] / mnp[0]);
            depths[threadIdx.x] = expf(lmn + lr * ((float)threadIdx.x * (1.0f / (DD - 1))));
        } else if (threadIdx.x < DD + SS) {
            int s = threadIdx.x - DD;
            float P[3][4];
            for (int i = 0; i < 3; ++i)
                for (int j = 0; j < 4; ++j) {
                    float a = 0.f;
                    for (int k = 0; k < 4; ++k)
                        a += Ks[s * 16 + i * 4 + k] * ext[s * 16 + k * 4 + j];
                    P[i][j] = a;
                }
            for (int i = 0; i < 3; ++i) {
                for (int j = 0; j < 3; ++j) {
                    float a = 0.f;
                    for (int k = 0; k < 3; ++k)
                        a += P[i][k] * invK[k * 4 + j];
                    mats[s * 12 + i * 3 + j] = a;
                }
                mats[s * 12 + 9 + i] = P[i][3];
            }
        }
    }
}

// Main: block = 8x8 pixel tile x 4 consecutive depths (one depth per wave).
// Wave-uniform skip of fully-OOB (depth, source) pairs; scalar loads for the
// per-source matrices (uniform s) and depth (readfirstlane); float-side clamps.
__global__ __launch_bounds__(256, 6) void cost_kernel(
    const _Float16* __restrict__ curT, const _Float16* __restrict__ srcT,
    const float* __restrict__ mats, const float* __restrict__ depths,
    float* __restrict__ out)
{
    int tid = threadIdx.x;
    const int TX = WW / 8;                 // 12
    const int TY = HH / 8;                 // 8
    int bx = blockIdx.x;
    int dg  = bx / (TX * TY);              // 0..15
    int rem = bx % (TX * TY);
    int tyi = rem / TX;
    int txi = rem % TX;
    int lane = tid & 63;
    int dsub = tid >> 6;                   // wave index = depth sub-index
    int d  = dg * 4 + dsub;
    int px = txi * 8 + (lane & 7);
    int py = tyi * 8 + (lane >> 3);
    int n  = py * WW + px;

    float x = (float)px + 0.5f;
    float y = (float)py + 0.5f;

    const H8* cp = (const H8*)(curT + (size_t)n * CC);
    H8 cA = cp[0], cB = cp[1];
    // d is wave-uniform; force scalar load of the depth
    float depth = depths[__builtin_amdgcn_readfirstlane(d)];

    float acc = 0.f;
#pragma unroll 2
    for (int s = 0; s < SS; ++s) {
        const float* m = &mats[s * 12];    // s loop-uniform -> s_load
        float m0 = m[0], m1 = m[1], m2 = m[2], m3 = m[3], m4 = m[4], m5 = m[5];
        float m6 = m[6], m7 = m[7], m8 = m[8], m9 = m[9], m10 = m[10], m11 = m[11];
        float qx = m0 * x + m1 * y + m2;
        float qy = m3 * x + m4 * y + m5;
        float qz = m6 * x + m7 * y + m8;
        float pz = depth * qz + m11;
        bool ok = pz > 0.f;
        float r = __builtin_amdgcn_rcpf(pz + 1e-8f);   // u = px/(z+EPS) per ref
        float u = (depth * qx + m9)  * r - 0.5f;
        float v = (depth * qy + m10) * r - 0.5f;
        // wave-uniform skip: contribution is exactly 0 when z<=0 or all 4 taps OOB
        bool contrib = ok && (u > -1.f) && (u < (float)WW) && (v > -1.f) && (v < (float)HH);
        if (__ballot(contrib) == 0ull) continue;
        // float-side clamps keep both taps of each pair inside the padded image
        // and in the zero border when OOB (v_med3_f32); !ok -> far border
        float uc = ok ? fminf(fmaxf(u, -2.0f), 96.5f) : -2.0f;
        float vc = ok ? fminf(fmaxf(v, -1.0f), 64.5f) : -1.0f;
        float x0f = floorf(uc), y0f = floorf(vc);
        float wx = uc - x0f, wy = vc - y0f;
        int x0p = (int)x0f + 2;                  // [0, 98]
        int y0p = (int)y0f + 1;                  // [0, 65]
        int y1p = min(y0p + 1, PH - 1);          // [1, 65]
        const _Float16* sbase = srcT + (size_t)s * (PN * CC);
        const H8* r0 = (const H8*)(sbase + (size_t)(y0p * PW + x0p) * CC);
        const H8* r1 = (const H8*)(sbase + (size_t)(y1p * PW + x0p) * CC);
        H8 a0 = r0[0], a1 = r0[1], a2 = r0[2], a3 = r0[3];   // row0: left|right tap
        H8 b0 = r1[0], b1 = r1[1], b2 = r1[2], b3 = r1[3];   // row1: left|right tap
        float dL0 = 0.f, dR0 = 0.f, dL1 = 0.f, dR1 = 0.f;
#pragma unroll
        for (int q = 0; q < 4; ++q) {
            dL0 = __builtin_amdgcn_fdot2(a0.v[q], cA.v[q], dL0, false);
            dL0 = __builtin_amdgcn_fdot2(a1.v[q], cB.v[q], dL0, false);
            dR0 = __builtin_amdgcn_fdot2(a2.v[q], cA.v[q], dR0, false);
            dR0 = __builtin_amdgcn_fdot2(a3.v[q], cB.v[q], dR0, false);
            dL1 = __builtin_amdgcn_fdot2(b0.v[q], cA.v[q], dL1, false);
            dL1 = __builtin_amdgcn_fdot2(b1.v[q], cB.v[q], dL1, false);
            dR1 = __builtin_amdgcn_fdot2(b2.v[q], cA.v[q], dR1, false);
            dR1 = __builtin_amdgcn_fdot2(b3.v[q], cB.v[q], dR1, false);
        }
        float d0 = dL0 + wx * (dR0 - dL0);
        float d1 = dL1 + wx * (dR1 - dL1);
        acc += d0 + wy * (d1 - d0);
    }
    out[(size_t)d * NN + n] = acc;                      // cost_volume
    out[(size_t)DD * NN + (size_t)d * NN + n] = depth;  // depth_planes
}

extern "C" void kernel_launch(void* const* d_in, const int* in_sizes, int n_in,
                              void* d_out, int out_size, void* d_ws, size_t ws_size,
                              hipStream_t stream) {
    const float* cur  = (const float*)d_in[0];
    const float* src  = (const float*)d_in[1];
    const float* ext  = (const float*)d_in[2];
    const float* Ks   = (const float*)d_in[3];
    const float* invK = (const float*)d_in[4];
    const float* mn   = (const float*)d_in[5];
    const float* mx   = (const float*)d_in[6];
    float* out = (float*)d_out;

    char* ws = (char*)d_ws;
    _Float16* srcT = (_Float16*)ws;                     // S*PN*C halfs ≈ 1.69 MB
    _Float16* curT = srcT + (size_t)SS * PN * CC;       // N*C halfs
    float* mats    = (float*)(curT + (size_t)NN * CC);  // 96
    float* depths  = mats + SS * 12;                    // 64

    int prepThreads = SS * PN + NN;                     // 58944
    int prepBlocks = (prepThreads + 255) / 256;         // 231
    prep_kernel<<<prepBlocks, 256, 0, stream>>>(cur, src, ext, Ks, invK, mn, mx,
                                                srcT, curT, mats, depths);
    cost_kernel<<<(DD / 4) * (WW / 8) * (HH / 8), 256, 0, stream>>>(curT, srcT, mats, depths, out);
}